// Round 3
// baseline (437.535 us; speedup 1.0000x reference)
//
#include <hip/hip_runtime.h>
#include <stdint.h>

#define BATCH 16384
#define IN_F 2048
#define OUT_F 2048

typedef unsigned short u16;
typedef __attribute__((ext_vector_type(8))) short bf16x8;
typedef __attribute__((ext_vector_type(4))) float f32x4;

__device__ __forceinline__ u16 f2bf(float f) {
  union { float f; uint32_t u; } v; v.f = f;
  uint32_t u = v.u;
  u += 0x7FFFu + ((u >> 16) & 1u);   // round-to-nearest-even
  return (u16)(u >> 16);
}

// pack two fp32 -> two bf16 (round-half-up): 2 v_add + 1 v_perm
__device__ __forceinline__ uint32_t pk_bf16(float a, float b) {
  uint32_t ua = __float_as_uint(a) + 0x8000u;
  uint32_t ub = __float_as_uint(b) + 0x8000u;
  return __builtin_amdgcn_perm(ub, ua, 0x07060302u);  // [ua.b2,ua.b3,ub.b2,ub.b3]
}

// ---- prologue: (W*M) fp32 -> bf16, once (42 MB traffic ~ 8 us) ----

__global__ void cvt_w_kernel(const float4* __restrict__ w, const float4* __restrict__ m,
                             u16* __restrict__ out) {
  int i = blockIdx.x * 256 + threadIdx.x;
  float4 wv = w[i];
  float4 mv = m[i];
  uint2 p;
  p.x = (uint32_t)f2bf(wv.x * mv.x) | ((uint32_t)f2bf(wv.y * mv.y) << 16);
  p.y = (uint32_t)f2bf(wv.z * mv.z) | ((uint32_t)f2bf(wv.w * mv.w) << 16);
  ((uint2*)out)[i] = p;
}

// ---- async global->LDS 16B copy (m97 recipe) ----

__device__ __forceinline__ void async_cp16(const void* g, void* l) {
  __builtin_amdgcn_global_load_lds(
      (const __attribute__((address_space(1))) void*)g,
      (__attribute__((address_space(3))) void*)l,
      16, 0, 0);
}

// ---- GEMM: C[M][N] = A_f32[M][K] * B_bf16[N][K]^T + bias ----
// 128x128 tile, BK=32, 4 waves 2x2, 4x4 16x16x32 bf16 MFMA frags/wave.
// A staged as fp32 (16 KB tile, 8x16B chunks/row, XOR-swizzle r&7),
// converted to bf16 in registers after ds_read (pk_bf16). B staged bf16
// (8 KB, 4 chunks/row, XOR-swizzle (r>>1)&3 — round-2 verified, 0 conflicts).

__global__ __launch_bounds__(256) void gemm_xf32(const float* __restrict__ A,
                                                 const u16* __restrict__ B,
                                                 const float* __restrict__ bias,
                                                 float* __restrict__ C) {
  __shared__ float lsA[128 * 32];   // 16 KB
  __shared__ u16  lsB[128 * 32];    // 8 KB
  const int K = IN_F, N = OUT_F;
  const int tid = threadIdx.x;
  const int lane = tid & 63, wave = tid >> 6;
  const int waveM = (wave & 1) * 64, waveN = (wave >> 1) * 64;
  const long bm = (long)blockIdx.x * 128;
  const long bn = (long)blockIdx.y * 128;

  // A staging: 1024 16B slots; thread covers s = kk*256 + tid, kk=0..3.
  // slot s -> row r=s>>3, chunk c=s&7; holds global chunk c^(r&7).
  const float* gA[4];
  char* lA[4];
#pragma unroll
  for (int kk = 0; kk < 4; kk++) {
    const int s = kk * 256 + tid;
    const int r = s >> 3, c = s & 7;
    const int cg = c ^ (r & 7);
    gA[kk] = A + (bm + r) * K + cg * 4;
    lA[kk] = (char*)lsA + s * 16;
  }
  // B staging: 512 slots; s = kk*256 + tid, kk=0..1.
  // slot s -> row r=s>>2, chunk c=s&3; holds global chunk c^((r>>1)&3).
  const u16* gB[2];
  char* lB[2];
#pragma unroll
  for (int kk = 0; kk < 2; kk++) {
    const int s = kk * 256 + tid;
    const int r = s >> 2, c = s & 3;
    const int cg = c ^ ((r >> 1) & 3);
    gB[kk] = B + (bn + r) * K + cg * 8;
    lB[kk] = (char*)lsB + s * 16;
  }

  f32x4 acc[4][4];
#pragma unroll
  for (int i = 0; i < 4; i++)
#pragma unroll
    for (int j = 0; j < 4; j++)
#pragma unroll
      for (int r = 0; r < 4; r++) acc[i][j][r] = 0.0f;

  const int mrow = lane & 15;
  const int q = lane >> 4;        // k-quad: B chunk q (16B bf16), A chunks 2q,2q+1
  const int q2 = q * 2;

  for (int k0 = 0; k0 < K; k0 += 32) {
#pragma unroll
    for (int kk = 0; kk < 4; kk++) async_cp16(gA[kk] + k0, lA[kk]);
#pragma unroll
    for (int kk = 0; kk < 2; kk++) async_cp16(gB[kk] + k0, lB[kk]);
    __syncthreads();   // drains vmcnt: staged data visible

    bf16x8 af[4], bfr[4];
#pragma unroll
    for (int i = 0; i < 4; i++) {
      const int rr = waveM + i * 16 + mrow;
      const f32x4* rowp = (const f32x4*)lsA + rr * 8;
      f32x4 f0 = rowp[q2 ^ (rr & 7)];
      f32x4 f1 = rowp[(q2 + 1) ^ (rr & 7)];
      union { uint32_t u[4]; bf16x8 v; } cv;
      cv.u[0] = pk_bf16(f0[0], f0[1]);
      cv.u[1] = pk_bf16(f0[2], f0[3]);
      cv.u[2] = pk_bf16(f1[0], f1[1]);
      cv.u[3] = pk_bf16(f1[2], f1[3]);
      af[i] = cv.v;
    }
#pragma unroll
    for (int j = 0; j < 4; j++) {
      const int rr = waveN + j * 16 + mrow;
      bfr[j] = *(const bf16x8*)&lsB[rr * 32 + (q ^ ((rr >> 1) & 3)) * 8];
    }

#pragma unroll
    for (int i = 0; i < 4; i++)
#pragma unroll
      for (int j = 0; j < 4; j++)
        acc[i][j] = __builtin_amdgcn_mfma_f32_16x16x32_bf16(af[i], bfr[j], acc[i][j], 0, 0, 0);

    __syncthreads();   // ds_reads done before next stage overwrites LDS
  }

  // epilogue: C/D layout col=lane&15, row=(lane>>4)*4+r  [m89-verified]
  const int cn = lane & 15;
  const int crow = (lane >> 4) * 4;
#pragma unroll
  for (int j = 0; j < 4; j++) {
    const long n = bn + waveN + j * 16 + cn;
    const float bv = bias[n];
#pragma unroll
    for (int i = 0; i < 4; i++) {
      const long m0 = bm + waveM + i * 16 + crow;
      float* cp = C + m0 * N + n;
#pragma unroll
      for (int r = 0; r < 4; r++)
        cp[(long)r * N] = acc[i][j][r] + bv;
    }
  }
}

// ---- fallback (only if d_ws is too small): exact fp32, slow but correct ----

__global__ void naive_kernel(const float* __restrict__ x, const float* __restrict__ w,
                             const float* __restrict__ bias, const float* __restrict__ m,
                             float* __restrict__ out) {
  size_t idx = (size_t)blockIdx.x * 256 + threadIdx.x;
  int o = (int)(idx % OUT_F);
  size_t b = idx / OUT_F;
  float s = bias[o];
  const float* xr = x + b * IN_F;
  const float* wr = w + (size_t)o * IN_F;
  const float* mr = m + (size_t)o * IN_F;
  for (int k = 0; k < IN_F; k++) s += xr[k] * wr[k] * mr[k];
  out[idx] = s;
}

extern "C" void kernel_launch(void* const* d_in, const int* in_sizes, int n_in,
                              void* d_out, int out_size, void* d_ws, size_t ws_size,
                              hipStream_t stream) {
  const float* x = (const float*)d_in[0];
  const float* w = (const float*)d_in[1];
  const float* bias = (const float*)d_in[2];
  const float* mask = (const float*)d_in[3];
  float* out = (float*)d_out;

  const size_t wm_elems = (size_t)OUT_F * IN_F;       // 4.2M bf16 = 8.4 MB
  const size_t need = wm_elems * sizeof(u16);

  if (ws_size >= need) {
    u16* wm = (u16*)d_ws;
    cvt_w_kernel<<<(uint32_t)(wm_elems / 4 / 256), 256, 0, stream>>>((const float4*)w,
                                                                     (const float4*)mask, wm);
    gemm_xf32<<<dim3(BATCH / 128, OUT_F / 128), 256, 0, stream>>>(x, wm, bias, out);
  } else {
    naive_kernel<<<(uint32_t)(((size_t)BATCH * OUT_F) / 256), 256, 0, stream>>>(x, w, bias, mask, out);
  }
}